// Round 17
// baseline (228.704 us; speedup 1.0000x reference)
//
#include <hip/hip_runtime.h>
#include <hip/hip_bf16.h>
#include <stdint.h>

#define B_TOT 262144

typedef __attribute__((ext_vector_type(8))) short bf8;
typedef __attribute__((ext_vector_type(4))) float f32x4;

__device__ __forceinline__ uint32_t f2bf(float x) {
  uint32_t u = __float_as_uint(x);
  return (u + 0x7fffu + ((u >> 16) & 1u)) >> 16;   // RTN-even
}
__device__ __forceinline__ uint32_t pkbf(float lo, float hi) {
  union { __hip_bfloat162 b; uint32_t u; } c;
  c.b = __float22bfloat162_rn(make_float2(lo, hi));
  return c.u;
}
__device__ __forceinline__ bf8 mkfrag(uint32_t w0, uint32_t w1, uint32_t w2, uint32_t w3) {
  union { uint32_t u[4]; bf8 v; } c;
  c.u[0] = w0; c.u[1] = w1; c.u[2] = w2; c.u[3] = w3;
  return c.v;
}

// ---------------- prep: W frags (16x16x32 true k-map) + W@a score vectors ----------
// 16x16x32 frag k-mapping: lane l, elem e: k = (e&3) + 4*((l>>4)&3) + 16*(e>>2); spatial = l&15.
__global__ __launch_bounds__(256) void prep_kernel(
    const float* __restrict__ W1, const float* __restrict__ a1s, const float* __restrict__ a1d,
    const float* __restrict__ W2, const float* __restrict__ a2s, const float* __restrict__ a2d,
    const float* __restrict__ Wo1, const float* __restrict__ Wo2,
    uint16_t* __restrict__ W1F, uint16_t* __restrict__ W2F,
    uint16_t* __restrict__ Wo1F, uint16_t* __restrict__ Wo2F, float* __restrict__ wvec)
{
  const int gid = blockIdx.x * 256 + threadIdx.x;
  const int e = gid & 7, li = (gid >> 3) & 63;
  const int kf = (e & 3) + 4 * ((li >> 4) & 3) + 16 * (e >> 2);
  const int sp = li & 15;
  if (gid < 4096) {   // W1F [ks2][t4]
    const int f = gid >> 9, t = f & 3, ks = f >> 2;
    const int k = ks * 32 + kf, row = t * 16 + sp;
    W1F[gid] = (uint16_t)f2bf(k < 35 ? W1[k * 64 + row] : 0.f);
  }
  if (gid < 4096) {   // W2F [ks2][t4]
    const int f = gid >> 9, t = f & 3, ks = f >> 2;
    const int k = ks * 32 + kf, row = t * 16 + sp;
    W2F[gid] = (uint16_t)f2bf(W2[k * 64 + row]);
  }
  if (gid < 49152) {  // Wo1F [ks6][t16]
    const int f = gid >> 9, t = f & 15, ks = f >> 4;
    const int k = ks * 32 + kf, col = t * 16 + sp;
    Wo1F[gid] = (uint16_t)f2bf(Wo1[k * 256 + col]);
  }
  if (gid < 32768) {  // Wo2F [ks8][t8]
    const int f = gid >> 9, t = f & 7, ks = f >> 3;
    const int k = ks * 32 + kf, col = t * 16 + sp;
    Wo2F[gid] = (uint16_t)f2bf(Wo2[k * 128 + col]);
  }
  if (gid < 224) {    // score vectors: [0..63]=W1@a1s (pad0), [64..127]=W1@a1d, [128..191]=W2@a2s, [192..255]=W2@a2d
    if (gid < 48) {
      float s = 0.f; if (gid < 35) for (int d = 0; d < 64; ++d) s += W1[gid * 64 + d] * a1s[d];
      wvec[gid] = s;
    } else if (gid < 96) {
      const int k = gid - 48; float s = 0.f;
      if (k < 35) for (int d = 0; d < 64; ++d) s += W1[k * 64 + d] * a1d[d];
      wvec[64 + k] = s;
    } else if (gid < 160) {
      const int k = gid - 96; float s = 0.f;
      for (int d = 0; d < 64; ++d) s += W2[k * 64 + d] * a2s[d];
      wvec[128 + k] = s;
    } else {
      const int k = gid - 160; float s = 0.f;
      for (int d = 0; d < 64; ++d) s += W2[k * 64 + d] * a2d[d];
      wvec[192 + k] = s;
    }
  }
}

// --------- softmax helper: alpha[3][3] from reduced ss/sd + counts ----------
__device__ __forceinline__ void att_alpha(const float (&ss)[3], const float (&sd)[3],
                                          uint32_t cp, float (&al)[3][3])
{
  #pragma unroll
  for (int i = 0; i < 3; ++i) {
    float ev[3]; float mx = -1e30f;
    #pragma unroll
    for (int j = 0; j < 3; ++j) {
      float s = ss[j] + sd[i];
      s = fmaxf(s, 0.2f * s);              // leaky_relu 0.2
      ev[j] = s;
      int c = (cp >> (2 * (3 * i + j))) & 3;
      mx = fmaxf(mx, c ? s : -1e30f);
    }
    float sum = 0.f;
    #pragma unroll
    for (int j = 0; j < 3; ++j) {
      int c = (cp >> (2 * (3 * i + j))) & 3;
      float p = (float)c * __expf(ev[j] - mx);
      al[i][j] = p; sum += p;
    }
    float inv = 1.0f / sum;
    #pragma unroll
    for (int j = 0; j < 3; ++j) al[i][j] *= inv;
  }
}

// ---- GAT kernel: 16x16x32, wave = 16 elems, no LDS; h2 -> global (96 words/elem) ----
__global__ __launch_bounds__(256) void gat_kernel(
    const float* __restrict__ obs, const float* __restrict__ act, const int* __restrict__ adj,
    const uint16_t* __restrict__ W1F, const uint16_t* __restrict__ W2F,
    const float* __restrict__ b1, const float* __restrict__ b2,
    const float* __restrict__ wvec, uint32_t* __restrict__ hb)
{
  const int tid = threadIdx.x;
  const int l = tid & 63, g = l >> 4, cl = l & 15;
  const int w = tid >> 6;
  const int g4 = g * 4;
  const int e = blockIdx.x * 64 + w * 16 + cl;
  const float* obs_e = obs + (size_t)e * 90;
  const float* act_e = act + (size_t)e * 15;
  // edge counts from adj directly (adj^T + I), 2 bits each
  uint32_t cp = 0;
  {
    const int* ap = adj + (size_t)e * 9;
    #pragma unroll
    for (int i = 0; i < 3; ++i)
      #pragma unroll
      for (int j = 0; j < 3; ++j) {
        uint32_t c = (uint32_t)ap[j * 3 + i] + (i == j ? 1u : 0u);
        cp |= c << (2 * (3 * i + j));
      }
  }

  // ===== GAT1: structured loads + f32 score dots =====
  bf8 xf0[3], xf1[3];
  float ss1[3], sd1[3];
  #pragma unroll
  for (int n = 0; n < 3; ++n) {
    const float* on = obs_e + n * 30;
    const float* an = act_e + n * 5;
    const float a0 = an[0], a1 = an[1], a2 = an[2], a3 = an[3], a4 = an[4];
    float2 r00 = *reinterpret_cast<const float2*>(on + g4);
    float2 r01 = *reinterpret_cast<const float2*>(on + g4 + 2);
    float2 r10 = *reinterpret_cast<const float2*>(on + 16 + g4);
    float2 r11 = *reinterpret_cast<const float2*>(on + (g == 3 ? 24 : 18 + g4)); // g3 dummy
    const float k6 = (g == 3) ? a0 : r11.x;
    const float k7 = (g == 3) ? a1 : r11.y;
    const float s0 = (g == 0) ? a2 : 0.f;
    const float s1 = (g == 0) ? a3 : 0.f;
    const float s2 = (g == 0) ? a4 : 0.f;
    float ss, sd;
    {
      float4 wS = *reinterpret_cast<const float4*>(wvec + g4);
      float4 wD = *reinterpret_cast<const float4*>(wvec + 64 + g4);
      ss = r00.x * wS.x + r00.y * wS.y; ss = fmaf(r01.x, wS.z, ss); ss = fmaf(r01.y, wS.w, ss);
      sd = r00.x * wD.x + r00.y * wD.y; sd = fmaf(r01.x, wD.z, sd); sd = fmaf(r01.y, wD.w, sd);
      wS = *reinterpret_cast<const float4*>(wvec + 16 + g4);
      wD = *reinterpret_cast<const float4*>(wvec + 80 + g4);
      ss = fmaf(r10.x, wS.x, ss); ss = fmaf(r10.y, wS.y, ss); ss = fmaf(k6, wS.z, ss); ss = fmaf(k7, wS.w, ss);
      sd = fmaf(r10.x, wD.x, sd); sd = fmaf(r10.y, wD.y, sd); sd = fmaf(k6, wD.z, sd); sd = fmaf(k7, wD.w, sd);
      wS = *reinterpret_cast<const float4*>(wvec + 32 + g4);
      wD = *reinterpret_cast<const float4*>(wvec + 96 + g4);
      ss = fmaf(s0, wS.x, ss); ss = fmaf(s1, wS.y, ss); ss = fmaf(s2, wS.z, ss);
      sd = fmaf(s0, wD.x, sd); sd = fmaf(s1, wD.y, sd); sd = fmaf(s2, wD.z, sd);
    }
    ss1[n] = ss; sd1[n] = sd;
    xf0[n] = mkfrag(pkbf(r00.x, r00.y), pkbf(r01.x, r01.y), pkbf(r10.x, r10.y), pkbf(k6, k7));
    xf1[n] = mkfrag(pkbf(s0, s1), pkbf(s2, 0.f), 0u, 0u);
  }
  f32x4 az[3][4];
  #pragma unroll
  for (int n = 0; n < 3; ++n)
    #pragma unroll
    for (int t = 0; t < 4; ++t)
      #pragma unroll
      for (int r = 0; r < 4; ++r) az[n][t][r] = 0.f;
  #pragma unroll
  for (int ks = 0; ks < 2; ++ks)
    #pragma unroll
    for (int t = 0; t < 4; ++t) {
      bf8 a = *reinterpret_cast<const bf8*>(W1F + (size_t)((ks * 4 + t) * 64 + l) * 8);
      #pragma unroll
      for (int n = 0; n < 3; ++n)
        az[n][t] = __builtin_amdgcn_mfma_f32_16x16x32_bf16(a, ks ? xf1[n] : xf0[n], az[n][t], 0, 0, 0);
    }
  #pragma unroll
  for (int n = 0; n < 3; ++n) {
    ss1[n] += __shfl_xor(ss1[n], 16); ss1[n] += __shfl_xor(ss1[n], 32);
    sd1[n] += __shfl_xor(sd1[n], 16); sd1[n] += __shfl_xor(sd1[n], 32);
  }

  // ===== attention1: ELU agg + next scores; pack -> Ph word-pairs =====
  uint32_t Ph[3][4][2];
  float ss2[3] = {0, 0, 0}, sd2[3] = {0, 0, 0};
  {
    float al[3][3];
    att_alpha(ss1, sd1, cp, al);
    #pragma unroll
    for (int t = 0; t < 4; ++t) {
      float4 b4 = *reinterpret_cast<const float4*>(b1 + t * 16 + g4);
      float4 s4 = *reinterpret_cast<const float4*>(wvec + 128 + t * 16 + g4);
      float4 d4 = *reinterpret_cast<const float4*>(wvec + 192 + t * 16 + g4);
      const float bv[4] = {b4.x, b4.y, b4.z, b4.w};
      const float sv[4] = {s4.x, s4.y, s4.z, s4.w};
      const float dv[4] = {d4.x, d4.y, d4.z, d4.w};
      #pragma unroll
      for (int i = 0; i < 3; ++i) {
        float hv[4];
        #pragma unroll
        for (int r = 0; r < 4; ++r) {
          float v = bv[r];
          v = fmaf(al[i][0], az[0][t][r], v);
          v = fmaf(al[i][1], az[1][t][r], v);
          v = fmaf(al[i][2], az[2][t][r], v);
          v = v > 0.f ? v : (__expf(v) - 1.f);   // ELU
          ss2[i] = fmaf(v, sv[r], ss2[i]);
          sd2[i] = fmaf(v, dv[r], sd2[i]);
          hv[r] = v;
        }
        Ph[i][t][0] = pkbf(hv[0], hv[1]);
        Ph[i][t][1] = pkbf(hv[2], hv[3]);
      }
    }
  }
  #pragma unroll
  for (int i = 0; i < 3; ++i) {
    ss2[i] += __shfl_xor(ss2[i], 16); ss2[i] += __shfl_xor(ss2[i], 32);
    sd2[i] += __shfl_xor(sd2[i], 16); sd2[i] += __shfl_xor(sd2[i], 32);
  }

  // ===== GAT2: B-frag = concat of two Ph tiles (C-row == B-k identity) =====
  f32x4 a2z[3][4];
  #pragma unroll
  for (int n = 0; n < 3; ++n)
    #pragma unroll
    for (int t = 0; t < 4; ++t)
      #pragma unroll
      for (int r = 0; r < 4; ++r) a2z[n][t][r] = 0.f;
  #pragma unroll
  for (int ks = 0; ks < 2; ++ks) {
    bf8 br[3];
    #pragma unroll
    for (int n = 0; n < 3; ++n)
      br[n] = mkfrag(Ph[n][2 * ks][0], Ph[n][2 * ks][1], Ph[n][2 * ks + 1][0], Ph[n][2 * ks + 1][1]);
    #pragma unroll
    for (int t = 0; t < 4; ++t) {
      bf8 aW = *reinterpret_cast<const bf8*>(W2F + (size_t)((ks * 4 + t) * 64 + l) * 8);
      #pragma unroll
      for (int n = 0; n < 3; ++n)
        a2z[n][t] = __builtin_amdgcn_mfma_f32_16x16x32_bf16(aW, br[n], a2z[n][t], 0, 0, 0);
    }
  }

  // ===== attention2: agg (no ELU) -> h2 global (uint2 word-pairs, 96 words/elem) =====
  {
    float al[3][3];
    att_alpha(ss2, sd2, cp, al);
    uint32_t* hcol = hb + (size_t)e * 96;
    #pragma unroll
    for (int t = 0; t < 4; ++t) {
      float4 b4 = *reinterpret_cast<const float4*>(b2 + t * 16 + g4);
      const float bv[4] = {b4.x, b4.y, b4.z, b4.w};
      #pragma unroll
      for (int i = 0; i < 3; ++i) {
        float hv[4];
        #pragma unroll
        for (int r = 0; r < 4; ++r) {
          float v = bv[r];
          v = fmaf(al[i][0], a2z[0][t][r], v);
          v = fmaf(al[i][1], a2z[1][t][r], v);
          v = fmaf(al[i][2], a2z[2][t][r], v);
          hv[r] = v;
        }
        *reinterpret_cast<uint2*>(hcol + i * 32 + t * 8 + 2 * g) =
            make_uint2(pkbf(hv[0], hv[1]), pkbf(hv[2], hv[3]));
      }
    }
  }
}

// ---- MLP kernel: block-coop over 64 elems; h from global; y1 LDS; 16x16x32 ----
__global__ __launch_bounds__(256) void mlp_kernel(
    const uint32_t* __restrict__ hb,
    const uint16_t* __restrict__ Wo1F, const float* __restrict__ bo1,
    const float* __restrict__ g1, const float* __restrict__ be1,
    const uint16_t* __restrict__ Wo2F, const float* __restrict__ bo2,
    const float* __restrict__ g2, const float* __restrict__ be2,
    const float* __restrict__ Wo3, const float* __restrict__ bo3,
    float* __restrict__ out)
{
  __shared__ __align__(16) uint32_t buf[8320];   // y1: [elem][feat2] stride 130 (33,280 B)
  __shared__ float part[1024];                   // 4 KB
  const int tid = threadIdx.x;
  const int l = tid & 63, g = l >> 4, cl = l & 15;
  const int w = tid >> 6;
  const int g4 = g * 4;
  const int e0 = blockIdx.x * 64;

  // ===== MLP1: wave w -> feat tiles w*4..w*4+3 (64 feats) for all 64 elems =====
  const int ft0 = w * 4;
  f32x4 acc[4][4];                              // [t][eg]
  #pragma unroll
  for (int t = 0; t < 4; ++t) {
    float4 b4 = *reinterpret_cast<const float4*>(bo1 + (ft0 + t) * 16 + g4);
    #pragma unroll
    for (int eg = 0; eg < 4; ++eg) {
      acc[t][eg][0] = b4.x; acc[t][eg][1] = b4.y; acc[t][eg][2] = b4.z; acc[t][eg][3] = b4.w;
    }
  }
  #pragma unroll
  for (int ks = 0; ks < 6; ++ks) {
    bf8 bfr[4];
    #pragma unroll
    for (int eg = 0; eg < 4; ++eg) {
      const uint32_t* p0 = hb + (size_t)(e0 + eg * 16 + cl) * 96 + ks * 16 + 2 * g;
      uint2 u0 = *reinterpret_cast<const uint2*>(p0);
      uint2 u1 = *reinterpret_cast<const uint2*>(p0 + 8);
      bfr[eg] = mkfrag(u0.x, u0.y, u1.x, u1.y);
    }
    #pragma unroll
    for (int t = 0; t < 4; ++t) {
      bf8 a = *reinterpret_cast<const bf8*>(Wo1F + (size_t)((ks * 16 + ft0 + t) * 64 + l) * 8);
      #pragma unroll
      for (int eg = 0; eg < 4; ++eg)
        acc[t][eg] = __builtin_amdgcn_mfma_f32_16x16x32_bf16(a, bfr[eg], acc[t][eg], 0, 0, 0);
    }
  }
  // LN1 partials (wave's 64 feats per elem)
  {
    float psm[4] = {0, 0, 0, 0}, psq[4] = {0, 0, 0, 0};
    #pragma unroll
    for (int t = 0; t < 4; ++t)
      #pragma unroll
      for (int eg = 0; eg < 4; ++eg)
        #pragma unroll
        for (int r = 0; r < 4; ++r) {
          const float v = acc[t][eg][r]; psm[eg] += v; psq[eg] = fmaf(v, v, psq[eg]);
        }
    #pragma unroll
    for (int eg = 0; eg < 4; ++eg) {
      psm[eg] += __shfl_xor(psm[eg], 16); psm[eg] += __shfl_xor(psm[eg], 32);
      psq[eg] += __shfl_xor(psq[eg], 16); psq[eg] += __shfl_xor(psq[eg], 32);
      if (g == 0) {
        part[w * 64 + eg * 16 + cl] = psm[eg];
        part[256 + w * 64 + eg * 16 + cl] = psq[eg];
      }
    }
  }
  __syncthreads();                              // B2: LN1 partials visible
  float mu1[4], rr1[4];
  #pragma unroll
  for (int eg = 0; eg < 4; ++eg) {
    const int ei = eg * 16 + cl;
    float s = part[ei] + part[64 + ei] + part[128 + ei] + part[192 + ei];
    float q = part[256 + ei] + part[320 + ei] + part[384 + ei] + part[448 + ei];
    mu1[eg] = s * (1.f / 256.f);
    rr1[eg] = rsqrtf(q * (1.f / 256.f) - mu1[eg] * mu1[eg] + 1e-5f);
  }
  // LN1 apply + lrelu + pack -> y1 LDS (stride 130)
  #pragma unroll
  for (int t = 0; t < 4; ++t) {
    float4 gg = *reinterpret_cast<const float4*>(g1 + (ft0 + t) * 16 + g4);
    float4 bb = *reinterpret_cast<const float4*>(be1 + (ft0 + t) * 16 + g4);
    const float gv[4] = {gg.x, gg.y, gg.z, gg.w};
    const float bv[4] = {bb.x, bb.y, bb.z, bb.w};
    #pragma unroll
    for (int eg = 0; eg < 4; ++eg) {
      float vv[4];
      #pragma unroll
      for (int r = 0; r < 4; ++r) {
        float v = (acc[t][eg][r] - mu1[eg]) * rr1[eg] * gv[r] + bv[r];
        vv[r] = fmaxf(v, 0.01f * v);
      }
      *reinterpret_cast<uint2*>(buf + (eg * 16 + cl) * 130 + (ft0 + t) * 8 + 2 * g) =
          make_uint2(pkbf(vv[0], vv[1]), pkbf(vv[2], vv[3]));
    }
  }
  __syncthreads();                              // B3: y1 complete

  // ===== MLP2: wave w -> feat tiles w*2..w*2+1 (32 feats) for all 64 elems =====
  const int ft2 = w * 2;
  f32x4 acc2[2][4];
  #pragma unroll
  for (int t = 0; t < 2; ++t) {
    float4 b4 = *reinterpret_cast<const float4*>(bo2 + (ft2 + t) * 16 + g4);
    #pragma unroll
    for (int eg = 0; eg < 4; ++eg) {
      acc2[t][eg][0] = b4.x; acc2[t][eg][1] = b4.y; acc2[t][eg][2] = b4.z; acc2[t][eg][3] = b4.w;
    }
  }
  #pragma unroll
  for (int ks = 0; ks < 8; ++ks) {
    bf8 bfr[4];
    #pragma unroll
    for (int eg = 0; eg < 4; ++eg) {
      const uint32_t* p0 = buf + (eg * 16 + cl) * 130 + ks * 16 + 2 * g;
      uint2 u0 = *reinterpret_cast<const uint2*>(p0);
      uint2 u1 = *reinterpret_cast<const uint2*>(p0 + 8);
      bfr[eg] = mkfrag(u0.x, u0.y, u1.x, u1.y);
    }
    #pragma unroll
    for (int t = 0; t < 2; ++t) {
      bf8 a = *reinterpret_cast<const bf8*>(Wo2F + (size_t)((ks * 8 + ft2 + t) * 64 + l) * 8);
      #pragma unroll
      for (int eg = 0; eg < 4; ++eg)
        acc2[t][eg] = __builtin_amdgcn_mfma_f32_16x16x32_bf16(a, bfr[eg], acc2[t][eg], 0, 0, 0);
    }
  }
  // LN2 partials (wave's 32 feats per elem)
  {
    float psm[4] = {0, 0, 0, 0}, psq[4] = {0, 0, 0, 0};
    #pragma unroll
    for (int t = 0; t < 2; ++t)
      #pragma unroll
      for (int eg = 0; eg < 4; ++eg)
        #pragma unroll
        for (int r = 0; r < 4; ++r) {
          const float v = acc2[t][eg][r]; psm[eg] += v; psq[eg] = fmaf(v, v, psq[eg]);
        }
    #pragma unroll
    for (int eg = 0; eg < 4; ++eg) {
      psm[eg] += __shfl_xor(psm[eg], 16); psm[eg] += __shfl_xor(psm[eg], 32);
      psq[eg] += __shfl_xor(psq[eg], 16); psq[eg] += __shfl_xor(psq[eg], 32);
      if (g == 0) {
        part[w * 64 + eg * 16 + cl] = psm[eg];
        part[256 + w * 64 + eg * 16 + cl] = psq[eg];
      }
    }
  }
  __syncthreads();                              // B4: LN2 partials visible
  {
    float dot[4];
    #pragma unroll
    for (int eg = 0; eg < 4; ++eg) {
      const int ei = eg * 16 + cl;
      float s = part[ei] + part[64 + ei] + part[128 + ei] + part[192 + ei];
      float q = part[256 + ei] + part[320 + ei] + part[384 + ei] + part[448 + ei];
      const float mu = s * (1.f / 128.f);
      const float rr = rsqrtf(q * (1.f / 128.f) - mu * mu + 1e-5f);
      float d = 0.f;
      #pragma unroll
      for (int t = 0; t < 2; ++t) {
        float4 gg = *reinterpret_cast<const float4*>(g2 + (ft2 + t) * 16 + g4);
        float4 bb = *reinterpret_cast<const float4*>(be2 + (ft2 + t) * 16 + g4);
        float4 ww = *reinterpret_cast<const float4*>(Wo3 + (ft2 + t) * 16 + g4);
        const float gv[4] = {gg.x, gg.y, gg.z, gg.w};
        const float bv[4] = {bb.x, bb.y, bb.z, bb.w};
        const float wv[4] = {ww.x, ww.y, ww.z, ww.w};
        #pragma unroll
        for (int r = 0; r < 4; ++r) {
          float v = (acc2[t][eg][r] - mu) * rr * gv[r] + bv[r];
          d = fmaf(fmaxf(v, 0.01f * v), wv[r], d);
        }
      }
      dot[eg] = d;
    }
    #pragma unroll
    for (int eg = 0; eg < 4; ++eg) {
      dot[eg] += __shfl_xor(dot[eg], 16); dot[eg] += __shfl_xor(dot[eg], 32);
      if (g == 0) part[512 + w * 64 + eg * 16 + cl] = dot[eg];
    }
  }
  __syncthreads();                              // B5: dot partials visible
  if (tid < 64) {
    out[e0 + tid] = part[512 + tid] + part[576 + tid] +
                    part[640 + tid] + part[704 + tid] + bo3[0];
  }
}

extern "C" void kernel_launch(void* const* d_in, const int* in_sizes, int n_in,
                              void* d_out, int out_size, void* d_ws, size_t ws_size,
                              hipStream_t stream) {
  const float* obs  = (const float*)d_in[0];
  const float* actn = (const float*)d_in[1];
  const int*   adj  = (const int*)d_in[2];
  const float* W1   = (const float*)d_in[3];
  const float* a1s  = (const float*)d_in[4];
  const float* a1d  = (const float*)d_in[5];
  const float* b1   = (const float*)d_in[6];
  const float* W2   = (const float*)d_in[7];
  const float* a2s  = (const float*)d_in[8];
  const float* a2d  = (const float*)d_in[9];
  const float* b2   = (const float*)d_in[10];
  const float* Wo1  = (const float*)d_in[11];
  const float* bo1  = (const float*)d_in[12];
  const float* g1   = (const float*)d_in[13];
  const float* be1  = (const float*)d_in[14];
  const float* Wo2  = (const float*)d_in[15];
  const float* bo2  = (const float*)d_in[16];
  const float* g2   = (const float*)d_in[17];
  const float* be2  = (const float*)d_in[18];
  const float* Wo3  = (const float*)d_in[19];
  const float* bo3  = (const float*)d_in[20];

  char* ws = (char*)d_ws;
  uint32_t* hb   = (uint32_t*)ws;                         // 100,663,296 B (96 words/elem)
  uint16_t* W1F  = (uint16_t*)(ws + 100663296);           // 8192 B
  uint16_t* W2F  = (uint16_t*)(ws + 100663296 + 8192);    // 8192 B
  uint16_t* Wo1F = (uint16_t*)(ws + 100663296 + 16384);   // 98304 B
  uint16_t* Wo2F = (uint16_t*)(ws + 100663296 + 114688);  // 65536 B
  float*    wvec = (float*)(ws + 100663296 + 180224);     // 1024 B
  float* outp = (float*)d_out;

  prep_kernel<<<192, 256, 0, stream>>>(W1, a1s, a1d, W2, a2s, a2d, Wo1, Wo2,
                                       W1F, W2F, Wo1F, Wo2F, wvec);
  gat_kernel<<<4096, 256, 0, stream>>>(obs, actn, adj, W1F, W2F, b1, b2, wvec, hb);
  mlp_kernel<<<4096, 256, 0, stream>>>(hb, Wo1F, bo1, g1, be1, Wo2F, bo2, g2, be2,
                                       Wo3, bo3, outp);
}

// Round 18
// 111.283 us; speedup vs baseline: 2.0552x; 2.0552x over previous
//
#include <hip/hip_runtime.h>
#include <hip/hip_bf16.h>
#include <stdint.h>

#define B_TOT 262144

typedef __attribute__((ext_vector_type(8))) short bf8;
typedef __attribute__((ext_vector_type(16))) float f32x16;

__device__ __forceinline__ float bf2f(uint32_t u)   { return __uint_as_float(u << 16); }
__device__ __forceinline__ float bfhi2f(uint32_t u) { return __uint_as_float(u & 0xffff0000u); }
__device__ __forceinline__ uint32_t f2bf(float x) {
  uint32_t u = __float_as_uint(x);
  return (u + 0x7fffu + ((u >> 16) & 1u)) >> 16;   // RTN-even
}
__device__ __forceinline__ uint32_t pkbf(float lo, float hi) {
  union { __hip_bfloat162 b; uint32_t u; } c;
  c.b = __float22bfloat162_rn(make_float2(lo, hi));
  return c.u;
}
__device__ __forceinline__ bf8 mkfrag(uint32_t w0, uint32_t w1, uint32_t w2, uint32_t w3) {
  union { uint32_t u[4]; bf8 v; } c;
  c.u[0] = w0; c.u[1] = w1; c.u[2] = w2; c.u[3] = w3;
  return c.v;
}
__device__ __forceinline__ bf8 u4bf8(uint4 v) {
  union { uint4 u; bf8 b; } c; c.u = v; return c.b;
}
// swizzled uint4 index for (column c, 16B-group q): spreads groups across banks
__device__ __forceinline__ int swz(int c, int q) { return c * 16 + (q ^ (c & 15)); }

// ---------------- prep: adj counts, W frags (true k-map), W@a score vectors ----------
// A/B frag k-mapping for mfma_32x32x16: lane l, elem e: k = 8*(e>>2)+4*(l>>5)+(e&3).
__global__ __launch_bounds__(256) void prep_kernel(
    const int* __restrict__ adj,
    const float* __restrict__ W1, const float* __restrict__ a1s, const float* __restrict__ a1d,
    const float* __restrict__ W2, const float* __restrict__ a2s, const float* __restrict__ a2d,
    const float* __restrict__ Wo1, const float* __restrict__ Wo2,
    uint32_t* __restrict__ cntp, uint16_t* __restrict__ W1F, uint16_t* __restrict__ W2F,
    uint16_t* __restrict__ Wo1F, uint16_t* __restrict__ Wo2F, float* __restrict__ wvec)
{
  const int gid = blockIdx.x * 256 + threadIdx.x;
  if (gid < B_TOT) {
    uint32_t cpv = 0;
    const int* ap = adj + (size_t)gid * 9;
    #pragma unroll
    for (int i = 0; i < 3; ++i)
      #pragma unroll
      for (int j = 0; j < 3; ++j) {
        uint32_t c = (uint32_t)ap[j * 3 + i] + (i == j ? 1u : 0u);  // adj^T + I
        cpv |= c << (2 * (3 * i + j));
      }
    cntp[gid] = cpv;
  }
  const int e = gid & 7, li = (gid >> 3) & 63;
  const int kfrag = 8 * (e >> 2) + 4 * (li >> 5) + (e & 3);
  if (gid < 3072) {   // W1^T frags [ks3][t2]
    const int f = gid >> 9, t = f & 1, ks = f >> 1;
    const int k = ks * 16 + kfrag, row = t * 32 + (li & 31);
    W1F[gid] = (uint16_t)f2bf(k < 35 ? W1[k * 64 + row] : 0.f);
  }
  if (gid < 4096) {   // W2^T frags [ks4][t2]
    const int f = gid >> 9, t = f & 1, ks = f >> 1;
    const int k = ks * 16 + kfrag, row = t * 32 + (li & 31);
    W2F[gid] = (uint16_t)f2bf(W2[k * 64 + row]);
  }
  if (gid < 49152) {  // Wo1^T frags [ks12][t8]
    const int rr = gid >> 9, t = rr & 7, ks = rr >> 3;
    const int k = ks * 16 + kfrag, col = t * 32 + (li & 31);
    Wo1F[gid] = (uint16_t)f2bf(Wo1[k * 256 + col]);
  }
  if (gid < 32768) {  // Wo2^T frags [ks16][t4]
    const int rr = gid >> 9, t = rr & 3, ks = rr >> 2;
    const int k = ks * 16 + kfrag, col = t * 32 + (li & 31);
    Wo2F[gid] = (uint16_t)f2bf(Wo2[k * 128 + col]);
  }
  if (gid < 224) {    // score vectors: [0..63]=W1@a1s (pad), [64..127]=W1@a1d, [128..191]=W2@a2s, [192..255]=W2@a2d
    if (gid < 48) {
      float s = 0.f; if (gid < 35) for (int d = 0; d < 64; ++d) s += W1[gid * 64 + d] * a1s[d];
      wvec[gid] = s;
    } else if (gid < 96) {
      const int k = gid - 48; float s = 0.f;
      if (k < 35) for (int d = 0; d < 64; ++d) s += W1[k * 64 + d] * a1d[d];
      wvec[64 + k] = s;
    } else if (gid < 160) {
      const int k = gid - 96; float s = 0.f;
      for (int d = 0; d < 64; ++d) s += W2[k * 64 + d] * a2s[d];
      wvec[128 + k] = s;
    } else {
      const int k = gid - 160; float s = 0.f;
      for (int d = 0; d < 64; ++d) s += W2[k * 64 + d] * a2d[d];
      wvec[192 + k] = s;
    }
  }
}

// --------- softmax helper: alpha[3][3] from reduced ss/sd + counts ----------
__device__ __forceinline__ void att_alpha(const float (&ss)[3], const float (&sd)[3],
                                          uint32_t cp, float (&al)[3][3])
{
  #pragma unroll
  for (int i = 0; i < 3; ++i) {
    float ev[3]; float mx = -1e30f;
    #pragma unroll
    for (int j = 0; j < 3; ++j) {
      float s = ss[j] + sd[i];
      s = fmaxf(s, 0.2f * s);              // leaky_relu 0.2
      ev[j] = s;
      int c = (cp >> (2 * (3 * i + j))) & 3;
      mx = fmaxf(mx, c ? s : -1e30f);
    }
    float sum = 0.f;
    #pragma unroll
    for (int j = 0; j < 3; ++j) {
      int c = (cp >> (2 * (3 * i + j))) & 3;
      float p = (float)c * __expf(ev[j] - mx);
      al[i][j] = p; sum += p;
    }
    float inv = 1.0f / sum;
    #pragma unroll
    for (int j = 0; j < 3; ++j) al[i][j] *= inv;
  }
}

// attention1: ELU + next-layer score dots; Ph to registers (reg-order pairwise pack)
__device__ __forceinline__ void attention1(const f32x16 (&az)[3][2],
    const float (&ss)[3], const float (&sd)[3], uint32_t cp, int hi,
    const float* __restrict__ bvec, const float* __restrict__ nxs, const float* __restrict__ nxd,
    uint32_t (&Ph)[3][16], float (&ss2)[3], float (&sd2)[3])
{
  float al[3][3];
  att_alpha(ss, sd, cp, al);
  #pragma unroll
  for (int t = 0; t < 2; ++t) {
    float bv[16], nsv[16], ndv[16];
    #pragma unroll
    for (int rq = 0; rq < 4; ++rq) {
      float4 b4 = *reinterpret_cast<const float4*>(bvec + t * 32 + rq * 8 + hi * 4);
      float4 s4 = *reinterpret_cast<const float4*>(nxs + t * 32 + rq * 8 + hi * 4);
      float4 d4 = *reinterpret_cast<const float4*>(nxd + t * 32 + rq * 8 + hi * 4);
      bv[4 * rq + 0] = b4.x; bv[4 * rq + 1] = b4.y; bv[4 * rq + 2] = b4.z; bv[4 * rq + 3] = b4.w;
      nsv[4 * rq + 0] = s4.x; nsv[4 * rq + 1] = s4.y; nsv[4 * rq + 2] = s4.z; nsv[4 * rq + 3] = s4.w;
      ndv[4 * rq + 0] = d4.x; ndv[4 * rq + 1] = d4.y; ndv[4 * rq + 2] = d4.z; ndv[4 * rq + 3] = d4.w;
    }
    #pragma unroll
    for (int i = 0; i < 3; ++i) {
      float hv[16];
      #pragma unroll
      for (int r = 0; r < 16; ++r) {
        float v = bv[r];
        v = fmaf(al[i][0], az[0][t][r], v);
        v = fmaf(al[i][1], az[1][t][r], v);
        v = fmaf(al[i][2], az[2][t][r], v);
        v = v > 0.f ? v : (__expf(v) - 1.f);          // ELU
        ss2[i] = fmaf(v, nsv[r], ss2[i]); sd2[i] = fmaf(v, ndv[r], sd2[i]);
        hv[r] = v;
      }
      #pragma unroll
      for (int p = 0; p < 8; ++p) Ph[i][t * 8 + p] = pkbf(hv[2 * p], hv[2 * p + 1]);
    }
  }
}

// attention2: no ELU; packs h2 and writes 2 x b128 per (i,t) to the swizzled column
__device__ __forceinline__ void attention2(const f32x16 (&az)[3][2],
    const float (&ss)[3], const float (&sd)[3], uint32_t cp, int hi,
    const float* __restrict__ bvec, uint4* __restrict__ b4p, int c_own)
{
  float al[3][3];
  att_alpha(ss, sd, cp, al);
  #pragma unroll
  for (int t = 0; t < 2; ++t) {
    float bv[16];
    #pragma unroll
    for (int rq = 0; rq < 4; ++rq) {
      float4 b4 = *reinterpret_cast<const float4*>(bvec + t * 32 + rq * 8 + hi * 4);
      bv[4 * rq + 0] = b4.x; bv[4 * rq + 1] = b4.y; bv[4 * rq + 2] = b4.z; bv[4 * rq + 3] = b4.w;
    }
    #pragma unroll
    for (int i = 0; i < 3; ++i) {
      float hv[16];
      #pragma unroll
      for (int r = 0; r < 16; ++r) {
        float v = bv[r];
        v = fmaf(al[i][0], az[0][t][r], v);
        v = fmaf(al[i][1], az[1][t][r], v);
        v = fmaf(al[i][2], az[2][t][r], v);
        hv[r] = v;
      }
      uint32_t w0 = pkbf(hv[0], hv[1]),  w1 = pkbf(hv[2], hv[3]);
      uint32_t w2 = pkbf(hv[4], hv[5]),  w3 = pkbf(hv[6], hv[7]);
      uint32_t w4 = pkbf(hv[8], hv[9]),  w5 = pkbf(hv[10], hv[11]);
      uint32_t w6 = pkbf(hv[12], hv[13]), w7 = pkbf(hv[14], hv[15]);
      b4p[swz(c_own, i * 4 + t * 2 + 0)] = make_uint4(w0, w1, w2, w3);
      b4p[swz(c_own, i * 4 + t * 2 + 1)] = make_uint4(w4, w5, w6, w7);
    }
  }
}

// ---- fused: GAT per-wave (32 elems) -> block-cooperative MLP; column-major swizzled LDS
__global__ __launch_bounds__(256, 2) void fused_kernel(
    const float* __restrict__ obs, const float* __restrict__ act,
    const uint32_t* __restrict__ cntp,
    const uint16_t* __restrict__ W1F, const uint16_t* __restrict__ W2F,
    const float* __restrict__ b1, const float* __restrict__ b2,
    const uint16_t* __restrict__ Wo1F, const float* __restrict__ bo1,
    const float* __restrict__ g1, const float* __restrict__ be1,
    const uint16_t* __restrict__ Wo2F, const float* __restrict__ bo2,
    const float* __restrict__ g2, const float* __restrict__ be2,
    const float* __restrict__ Wo3, const float* __restrict__ bo3,
    const float* __restrict__ wvec, float* __restrict__ out)
{
  __shared__ __align__(16) uint32_t buf[16384];   // 64 KB: 256 columns x 64 words (swizzled)
  __shared__ float part[1536];                    // 6 KB: LN partials + output partials
  uint4* b4p = (uint4*)buf;
  const uint4* b4c = (const uint4*)buf;
  const int tid = threadIdx.x;
  const int l = tid & 63, hi = l >> 5, col = l & 31;
  const int w = tid >> 6;
  const int eb = w * 32 + col;                 // element within block (GAT ownership)
  const int e = blockIdx.x * 128 + eb;
  const uint32_t cp = cntp[e];
  const float* obs_e = obs + (size_t)e * 90;
  const float* act_e = act + (size_t)e * 15;
  const int h4 = hi * 4;

  // ===== GAT layer 1: structured float2 x-loads (k-runs match frag layout) =====
  bf8 xf[3][3];                                // [ks][n]
  float ss1[3], sd1[3];
  #pragma unroll
  for (int n = 0; n < 3; ++n) {
    const float* on = obs_e + n * 30;
    const float* an = act_e + n * 5;
    const float a0 = an[0], a1 = an[1], a2 = an[2], a3 = an[3], a4 = an[4];
    float2 r00 = *reinterpret_cast<const float2*>(on + h4);        // k = h4+0,1
    float2 r01 = *reinterpret_cast<const float2*>(on + h4 + 2);    // k = h4+2,3
    float2 r10 = *reinterpret_cast<const float2*>(on + h4 + 8);
    float2 r11 = *reinterpret_cast<const float2*>(on + h4 + 10);
    float2 r20 = *reinterpret_cast<const float2*>(on + h4 + 16);
    float2 r21 = *reinterpret_cast<const float2*>(on + h4 + 18);
    float2 r30 = *reinterpret_cast<const float2*>(on + h4 + 24);   // hi0: 24,25  hi1: 28,29
    float2 r31 = *reinterpret_cast<const float2*>(hi ? (on + 24) : (on + 26)); // hi1 discarded
    const float k6 = hi ? a0 : r31.x;          // k = 26 (hi0) / 30=act0 (hi1)
    const float k7 = hi ? a1 : r31.y;          // k = 27 (hi0) / 31=act1 (hi1)
    const float s0 = hi ? 0.f : a2;            // k = 32..34 (hi0) / pad (hi1)
    const float s1 = hi ? 0.f : a3;
    const float s2 = hi ? 0.f : a4;
    // f32 score dots vs wvec (this lane's k-runs; hi-halves combine via shfl below)
    float ss, sd;
    {
      float4 wS = *reinterpret_cast<const float4*>(wvec + h4);
      float4 wD = *reinterpret_cast<const float4*>(wvec + 64 + h4);
      ss = r00.x * wS.x + r00.y * wS.y; ss = fmaf(r01.x, wS.z, ss); ss = fmaf(r01.y, wS.w, ss);
      sd = r00.x * wD.x + r00.y * wD.y; sd = fmaf(r01.x, wD.z, sd); sd = fmaf(r01.y, wD.w, sd);
      wS = *reinterpret_cast<const float4*>(wvec + h4 + 8);
      wD = *reinterpret_cast<const float4*>(wvec + 64 + h4 + 8);
      ss = fmaf(r10.x, wS.x, ss); ss = fmaf(r10.y, wS.y, ss); ss = fmaf(r11.x, wS.z, ss); ss = fmaf(r11.y, wS.w, ss);
      sd = fmaf(r10.x, wD.x, sd); sd = fmaf(r10.y, wD.y, sd); sd = fmaf(r11.x, wD.z, sd); sd = fmaf(r11.y, wD.w, sd);
      wS = *reinterpret_cast<const float4*>(wvec + h4 + 16);
      wD = *reinterpret_cast<const float4*>(wvec + 64 + h4 + 16);
      ss = fmaf(r20.x, wS.x, ss); ss = fmaf(r20.y, wS.y, ss); ss = fmaf(r21.x, wS.z, ss); ss = fmaf(r21.y, wS.w, ss);
      sd = fmaf(r20.x, wD.x, sd); sd = fmaf(r20.y, wD.y, sd); sd = fmaf(r21.x, wD.z, sd); sd = fmaf(r21.y, wD.w, sd);
      wS = *reinterpret_cast<const float4*>(wvec + h4 + 24);
      wD = *reinterpret_cast<const float4*>(wvec + 64 + h4 + 24);
      ss = fmaf(r30.x, wS.x, ss); ss = fmaf(r30.y, wS.y, ss); ss = fmaf(k6, wS.z, ss); ss = fmaf(k7, wS.w, ss);
      sd = fmaf(r30.x, wD.x, sd); sd = fmaf(r30.y, wD.y, sd); sd = fmaf(k6, wD.z, sd); sd = fmaf(k7, wD.w, sd);
      wS = *reinterpret_cast<const float4*>(wvec + h4 + 32);
      wD = *reinterpret_cast<const float4*>(wvec + 64 + h4 + 32);
      ss = fmaf(s0, wS.x, ss); ss = fmaf(s1, wS.y, ss); ss = fmaf(s2, wS.z, ss);
      sd = fmaf(s0, wD.x, sd); sd = fmaf(s1, wD.y, sd); sd = fmaf(s2, wD.z, sd);
    }
    ss1[n] = ss; sd1[n] = sd;
    xf[0][n] = mkfrag(pkbf(r00.x, r00.y), pkbf(r01.x, r01.y), pkbf(r10.x, r10.y), pkbf(r11.x, r11.y));
    xf[1][n] = mkfrag(pkbf(r20.x, r20.y), pkbf(r21.x, r21.y), pkbf(r30.x, r30.y), pkbf(k6, k7));
    xf[2][n] = mkfrag(pkbf(s0, s1), pkbf(s2, 0.f), 0u, 0u);
  }
  f32x16 az[3][2];
  #pragma unroll
  for (int n = 0; n < 3; ++n)
    #pragma unroll
    for (int t = 0; t < 2; ++t)
      #pragma unroll
      for (int r = 0; r < 16; ++r) az[n][t][r] = 0.f;
  #pragma unroll
  for (int ks = 0; ks < 3; ++ks)
    #pragma unroll
    for (int t = 0; t < 2; ++t) {
      bf8 a = *reinterpret_cast<const bf8*>(W1F + (size_t)(ks * 2 + t) * 512 + l * 8);
      #pragma unroll
      for (int n = 0; n < 3; ++n)
        az[n][t] = __builtin_amdgcn_mfma_f32_32x32x16_bf16(a, xf[ks][n], az[n][t], 0, 0, 0);
    }
  #pragma unroll
  for (int n = 0; n < 3; ++n) {
    ss1[n] += __shfl_xor(ss1[n], 32);
    sd1[n] += __shfl_xor(sd1[n], 32);
  }

  uint32_t Ph1[3][16];
  float ss2[3] = {0, 0, 0}, sd2[3] = {0, 0, 0};
  attention1(az, ss1, sd1, cp, hi, b1, wvec + 128, wvec + 192, Ph1, ss2, sd2);
  #pragma unroll
  for (int n = 0; n < 3; ++n) {
    ss2[n] += __shfl_xor(ss2[n], 32);
    sd2[n] += __shfl_xor(sd2[n], 32);
  }

  // ===== GAT layer 2 (Ph1 frags from regs) =====
  f32x16 a2[3][2];
  #pragma unroll
  for (int n = 0; n < 3; ++n)
    #pragma unroll
    for (int t = 0; t < 2; ++t)
      #pragma unroll
      for (int r = 0; r < 16; ++r) a2[n][t][r] = 0.f;
  #pragma unroll
  for (int ks = 0; ks < 4; ++ks) {
    #pragma unroll
    for (int t = 0; t < 2; ++t) {
      bf8 a = *reinterpret_cast<const bf8*>(W2F + (size_t)(ks * 2 + t) * 512 + l * 8);
      #pragma unroll
      for (int n = 0; n < 3; ++n) {
        bf8 br_ = mkfrag(Ph1[n][4 * ks], Ph1[n][4 * ks + 1], Ph1[n][4 * ks + 2], Ph1[n][4 * ks + 3]);
        a2[n][t] = __builtin_amdgcn_mfma_f32_32x32x16_bf16(a, br_, a2[n][t], 0, 0, 0);
      }
    }
  }

  // attention2 -> h2 packed into swizzled column (groups 0..11)
  attention2(a2, ss2, sd2, cp, hi, b2, b4p, hi * 128 + eb);
  __syncthreads();                                   // B1: h2 visible block-wide

  // ===== MLP1: wave w computes feats [64w,64w+64) for ALL 128 elems =====
  const int fb1 = w * 64;
  f32x16 acc[2][4];                                  // [t][eg]
  #pragma unroll
  for (int t = 0; t < 2; ++t)
    #pragma unroll
    for (int rq = 0; rq < 4; ++rq) {
      float4 b4 = *reinterpret_cast<const float4*>(bo1 + fb1 + t * 32 + rq * 8 + hi * 4);
      #pragma unroll
      for (int eg = 0; eg < 4; ++eg) {
        acc[t][eg][4 * rq + 0] = b4.x; acc[t][eg][4 * rq + 1] = b4.y;
        acc[t][eg][4 * rq + 2] = b4.z; acc[t][eg][4 * rq + 3] = b4.w;
      }
    }
  #pragma unroll
  for (int ks = 0; ks < 12; ++ks) {
    bf8 bfr[4];
    #pragma unroll
    for (int eg = 0; eg < 4; ++eg)
      bfr[eg] = u4bf8(b4c[swz(hi * 128 + eg * 32 + col, ks)]);
    #pragma unroll
    for (int t = 0; t < 2; ++t) {
      bf8 a = *reinterpret_cast<const bf8*>(Wo1F + (size_t)(ks * 8 + w * 2 + t) * 512 + l * 8);
      #pragma unroll
      for (int eg = 0; eg < 4; ++eg)
        acc[t][eg] = __builtin_amdgcn_mfma_f32_32x32x16_bf16(a, bfr[eg], acc[t][eg], 0, 0, 0);
    }
  }
  // LN1 partials (wave's 64 feats per elem)
  {
    float psm[4], psq[4];
    #pragma unroll
    for (int eg = 0; eg < 4; ++eg) { psm[eg] = 0.f; psq[eg] = 0.f; }
    #pragma unroll
    for (int t = 0; t < 2; ++t)
      #pragma unroll
      for (int eg = 0; eg < 4; ++eg)
        #pragma unroll
        for (int r = 0; r < 16; ++r) {
          const float v = acc[t][eg][r]; psm[eg] += v; psq[eg] = fmaf(v, v, psq[eg]);
        }
    #pragma unroll
    for (int eg = 0; eg < 4; ++eg) {
      psm[eg] += __shfl_xor(psm[eg], 32);
      psq[eg] += __shfl_xor(psq[eg], 32);
      if (hi == 0) {
        part[w * 128 + eg * 32 + col] = psm[eg];
        part[512 + w * 128 + eg * 32 + col] = psq[eg];
      }
    }
  }
  __syncthreads();                                   // B2: LN1 partials visible; h reads done
  float mu1[4], rr1[4];
  #pragma unroll
  for (int eg = 0; eg < 4; ++eg) {
    const int ei = eg * 32 + col;
    float s = part[ei] + part[128 + ei] + part[256 + ei] + part[384 + ei];
    float q = part[512 + ei] + part[640 + ei] + part[768 + ei] + part[896 + ei];
    mu1[eg] = s * (1.f / 256.f);
    rr1[eg] = rsqrtf(q * (1.f / 256.f) - mu1[eg] * mu1[eg] + 1e-5f);
  }
  // LN1 apply + lrelu + pack -> y1 b128 writes (groups w*4+t*2, +1); overwrites h (dead)
  #pragma unroll
  for (int t = 0; t < 2; ++t) {
    float gv[16], bv[16];
    #pragma unroll
    for (int rq = 0; rq < 4; ++rq) {
      float4 gg = *reinterpret_cast<const float4*>(g1 + fb1 + t * 32 + rq * 8 + hi * 4);
      float4 bb = *reinterpret_cast<const float4*>(be1 + fb1 + t * 32 + rq * 8 + hi * 4);
      gv[4 * rq + 0] = gg.x; gv[4 * rq + 1] = gg.y; gv[4 * rq + 2] = gg.z; gv[4 * rq + 3] = gg.w;
      bv[4 * rq + 0] = bb.x; bv[4 * rq + 1] = bb.y; bv[4 * rq + 2] = bb.z; bv[4 * rq + 3] = bb.w;
    }
    #pragma unroll
    for (int eg = 0; eg < 4; ++eg) {
      uint32_t wd[8];
      #pragma unroll
      for (int p = 0; p < 8; ++p) {
        float va = (acc[t][eg][2 * p]     - mu1[eg]) * rr1[eg] * gv[2 * p]     + bv[2 * p];
        float vb = (acc[t][eg][2 * p + 1] - mu1[eg]) * rr1[eg] * gv[2 * p + 1] + bv[2 * p + 1];
        va = fmaxf(va, 0.01f * va);
        vb = fmaxf(vb, 0.01f * vb);
        wd[p] = pkbf(va, vb);
      }
      const int c = hi * 128 + eg * 32 + col;
      b4p[swz(c, w * 4 + t * 2 + 0)] = make_uint4(wd[0], wd[1], wd[2], wd[3]);
      b4p[swz(c, w * 4 + t * 2 + 1)] = make_uint4(wd[4], wd[5], wd[6], wd[7]);
    }
  }
  __syncthreads();                                   // B4: y1 complete

  // ===== MLP2: wave w computes feats [32w,32w+32) for ALL 128 elems =====
  const int fb2 = w * 32;
  f32x16 acc2[4];
  #pragma unroll
  for (int rq = 0; rq < 4; ++rq) {
    float4 b4 = *reinterpret_cast<const float4*>(bo2 + fb2 + rq * 8 + hi * 4);
    #pragma unroll
    for (int eg = 0; eg < 4; ++eg) {
      acc2[eg][4 * rq + 0] = b4.x; acc2[eg][4 * rq + 1] = b4.y;
      acc2[eg][4 * rq + 2] = b4.z; acc2[eg][4 * rq + 3] = b4.w;
    }
  }
  #pragma unroll
  for (int ks = 0; ks < 16; ++ks) {
    bf8 bfr[4];
    #pragma unroll
    for (int eg = 0; eg < 4; ++eg)
      bfr[eg] = u4bf8(b4c[swz(hi * 128 + eg * 32 + col, ks)]);
    bf8 a = *reinterpret_cast<const bf8*>(Wo2F + (size_t)(ks * 4 + w) * 512 + l * 8);
    #pragma unroll
    for (int eg = 0; eg < 4; ++eg)
      acc2[eg] = __builtin_amdgcn_mfma_f32_32x32x16_bf16(a, bfr[eg], acc2[eg], 0, 0, 0);
  }
  // LN2 partials (wave's 32 feats per elem)
  {
    float psm[4], psq[4];
    #pragma unroll
    for (int eg = 0; eg < 4; ++eg) { psm[eg] = 0.f; psq[eg] = 0.f; }
    #pragma unroll
    for (int eg = 0; eg < 4; ++eg)
      #pragma unroll
      for (int r = 0; r < 16; ++r) {
        const float v = acc2[eg][r]; psm[eg] += v; psq[eg] = fmaf(v, v, psq[eg]);
      }
    #pragma unroll
    for (int eg = 0; eg < 4; ++eg) {
      psm[eg] += __shfl_xor(psm[eg], 32);
      psq[eg] += __shfl_xor(psq[eg], 32);
      if (hi == 0) {
        part[w * 128 + eg * 32 + col] = psm[eg];
        part[512 + w * 128 + eg * 32 + col] = psq[eg];
      }
    }
  }
  __syncthreads();                                   // B6: LN2 partials visible
  {
    float dot[4];
    #pragma unroll
    for (int eg = 0; eg < 4; ++eg) {
      const int ei = eg * 32 + col;
      float s = part[ei] + part[128 + ei] + part[256 + ei] + part[384 + ei];
      float q = part[512 + ei] + part[640 + ei] + part[768 + ei] + part[896 + ei];
      const float mu = s * (1.f / 128.f);
      const float rr = rsqrtf(q * (1.f / 128.f) - mu * mu + 1e-5f);
      float d = 0.f;
      #pragma unroll
      for (int rq = 0; rq < 4; ++rq) {
        float4 gg = *reinterpret_cast<const float4*>(g2 + fb2 + rq * 8 + hi * 4);
        float4 bb = *reinterpret_cast<const float4*>(be2 + fb2 + rq * 8 + hi * 4);
        float4 ww = *reinterpret_cast<const float4*>(Wo3 + fb2 + rq * 8 + hi * 4);
        float v;
        v = (acc2[eg][4 * rq + 0] - mu) * rr * gg.x + bb.x; d = fmaf(fmaxf(v, 0.01f * v), ww.x, d);
        v = (acc2[eg][4 * rq + 1] - mu) * rr * gg.y + bb.y; d = fmaf(fmaxf(v, 0.01f * v), ww.y, d);
        v = (acc2[eg][4 * rq + 2] - mu) * rr * gg.z + bb.z; d = fmaf(fmaxf(v, 0.01f * v), ww.z, d);
        v = (acc2[eg][4 * rq + 3] - mu) * rr * gg.w + bb.w; d = fmaf(fmaxf(v, 0.01f * v), ww.w, d);
      }
      dot[eg] = d;
    }
    #pragma unroll
    for (int eg = 0; eg < 4; ++eg) {
      dot[eg] += __shfl_xor(dot[eg], 32);
      if (hi == 0) part[1024 + w * 128 + eg * 32 + col] = dot[eg];
    }
  }
  __syncthreads();                                   // B7: dot partials visible
  if (tid < 128) {
    out[blockIdx.x * 128 + tid] = part[1024 + tid] + part[1152 + tid] +
                                  part[1280 + tid] + part[1408 + tid] + bo3[0];
  }
}

extern "C" void kernel_launch(void* const* d_in, const int* in_sizes, int n_in,
                              void* d_out, int out_size, void* d_ws, size_t ws_size,
                              hipStream_t stream) {
  const float* obs  = (const float*)d_in[0];
  const float* actn = (const float*)d_in[1];
  const int*   adj  = (const int*)d_in[2];
  const float* W1   = (const float*)d_in[3];
  const float* a1s  = (const float*)d_in[4];
  const float* a1d  = (const float*)d_in[5];
  const float* b1   = (const float*)d_in[6];
  const float* W2   = (const float*)d_in[7];
  const float* a2s  = (const float*)d_in[8];
  const float* a2d  = (const float*)d_in[9];
  const float* b2   = (const float*)d_in[10];
  const float* Wo1  = (const float*)d_in[11];
  const float* bo1  = (const float*)d_in[12];
  const float* g1   = (const float*)d_in[13];
  const float* be1  = (const float*)d_in[14];
  const float* Wo2  = (const float*)d_in[15];
  const float* bo2  = (const float*)d_in[16];
  const float* g2   = (const float*)d_in[17];
  const float* be2  = (const float*)d_in[18];
  const float* Wo3  = (const float*)d_in[19];
  const float* bo3  = (const float*)d_in[20];

  char* ws = (char*)d_ws;
  uint32_t* cntp = (uint32_t*)ws;                       // 1 MB
  uint16_t* W1F  = (uint16_t*)(ws + 1048576);           // 6144 B
  uint16_t* W2F  = (uint16_t*)(ws + 1048576 + 8192);    // 8192 B
  uint16_t* Wo1F = (uint16_t*)(ws + 1048576 + 16384);   // 98304 B
  uint16_t* Wo2F = (uint16_t*)(ws + 1048576 + 114688);  // 65536 B
  float*    wvec = (float*)(ws + 1048576 + 180224);     // 1024 B
  float* outp = (float*)d_out;

  prep_kernel<<<1024, 256, 0, stream>>>(adj, W1, a1s, a1d, W2, a2s, a2d, Wo1, Wo2,
                                        cntp, W1F, W2F, Wo1F, Wo2F, wvec);
  fused_kernel<<<2048, 256, 0, stream>>>(obs, actn, cntp, W1F, W2F, b1, b2,
                                         Wo1F, bo1, g1, be1, Wo2F, bo2, g2, be2,
                                         Wo3, bo3, wvec, outp);
}